// Round 1
// baseline (5550.999 us; speedup 1.0000x reference)
//
#include <hip/hip_runtime.h>

constexpr int MDIM = 128;          // feature dim
constexpr float GAMMA_C = 0.8f;
constexpr int ITERS = 20;          // inner^20(X) == inner^21(0); see analysis

// ---------------- CSR build ----------------
__global__ void hist_kernel(const int* __restrict__ dst, int* __restrict__ deg, int E) {
  int e = blockIdx.x * 256 + threadIdx.x;
  if (e < E) atomicAdd(&deg[dst[e]], 1);
}

__global__ __launch_bounds__(1024) void scan_kernel(const int* __restrict__ deg,
                                                    int* __restrict__ offs, int n) {
  __shared__ int buf[1024];
  __shared__ int carry_s;
  int t = threadIdx.x;
  if (t == 0) carry_s = 0;
  __syncthreads();
  for (int base = 0; base < n; base += 1024) {
    int v = (base + t < n) ? deg[base + t] : 0;
    buf[t] = v;
    __syncthreads();
    for (int off = 1; off < 1024; off <<= 1) {
      int x = (t >= off) ? buf[t - off] : 0;
      __syncthreads();
      buf[t] += x;
      __syncthreads();
    }
    int incl = buf[t];
    if (base + t < n) offs[base + t] = carry_s + incl - v;   // exclusive
    __syncthreads();                      // all reads of carry_s done
    if (t == 1023) carry_s = carry_s + incl;
    __syncthreads();                      // update visible
  }
  if (t == 0) offs[n] = carry_s;
}

__global__ void scatter_kernel(const int* __restrict__ src, const int* __restrict__ dst,
                               const float* __restrict__ w, const int* __restrict__ offs,
                               int* __restrict__ cur, int2* __restrict__ csr, int E) {
  int e = blockIdx.x * 256 + threadIdx.x;
  if (e < E) {
    int d = dst[e];
    int pos = offs[d] + atomicAdd(&cur[d], 1);
    csr[pos] = make_int2(src[e], __float_as_int(w[e]));
  }
}

// ---------------- gF = F^T F / (||F^T F||_F + eps) ----------------
__global__ void ff_kernel(const float* __restrict__ F, float* __restrict__ FF) {
  int idx = blockIdx.x * 256 + threadIdx.x;   // 16384 total
  int i = idx >> 7, j = idx & 127;
  float acc = 0.f;
  for (int k = 0; k < 128; ++k) acc += F[k * 128 + i] * F[k * 128 + j];
  FF[idx] = acc;
}

__global__ void normsq_kernel(const float* __restrict__ FF, float* __restrict__ s) {
  int idx = blockIdx.x * 256 + threadIdx.x;
  float v = FF[idx];
  float v2 = v * v;
  for (int off = 32; off > 0; off >>= 1) v2 += __shfl_down(v2, off, 64);
  __shared__ float partial[4];
  int lane = threadIdx.x & 63, wv = threadIdx.x >> 6;
  if (lane == 0) partial[wv] = v2;
  __syncthreads();
  if (threadIdx.x == 0) atomicAdd(s, partial[0] + partial[1] + partial[2] + partial[3]);
}

__global__ void scale_kernel(float* __restrict__ FF, const float* __restrict__ s) {
  int idx = blockIdx.x * 256 + threadIdx.x;
  FF[idx] *= 1.0f / (sqrtf(*s) + 1e-12f);
}

// ---------------- propagation: P[n] = sum_e w_e * Z[src_e], CSR gather ----------------
// 32 threads per node (float4 over 128 features), 8 nodes per 256-thread block.
__global__ __launch_bounds__(256) void prop_kernel(const float4* __restrict__ Zin,
                                                   float4* __restrict__ Pout,
                                                   const int* __restrict__ offs,
                                                   const int2* __restrict__ csr, int N) {
  int t = threadIdx.x & 31;
  int node = blockIdx.x * 8 + (threadIdx.x >> 5);
  if (node >= N) return;
  int beg = offs[node], end = offs[node + 1];
  float4 acc = make_float4(0.f, 0.f, 0.f, 0.f);
  for (int e = beg; e < end; ++e) {
    int2 sw = csr[e];
    float w = __int_as_float(sw.y);
    float4 z = Zin[sw.x * 32 + t];
    acc.x += w * z.x; acc.y += w * z.y; acc.z += w * z.z; acc.w += w * z.w;
  }
  Pout[node * 32 + t] = acc;
}

// ---------------- Z = gamma * P @ gF + X  (gF symmetric) ----------------
__global__ __launch_bounds__(256) void gemm_kernel(const float* __restrict__ P,
                                                   const float* __restrict__ X,
                                                   float* __restrict__ Z,
                                                   const float* __restrict__ gF, int N) {
  __shared__ float Pt[64][128];
  int n0 = blockIdx.x * 64;
  int rows = min(64, N - n0);
  int nload = rows * 32;                              // float4 count
  const float4* P4 = (const float4*)(P + (size_t)n0 * 128);
  float4* Pt4 = (float4*)&Pt[0][0];
  for (int i = threadIdx.x; i < nload; i += 256) Pt4[i] = P4[i];
  __syncthreads();
  int j4 = threadIdx.x & 31;
  int nl = threadIdx.x >> 5;                          // 0..7, 8 nodes each
  float4 acc[8];
#pragma unroll
  for (int r = 0; r < 8; ++r) acc[r] = make_float4(0.f, 0.f, 0.f, 0.f);
  const float4* g4 = (const float4*)gF;
#pragma unroll 4
  for (int k = 0; k < 128; ++k) {
    float4 g = g4[k * 32 + j4];
#pragma unroll
    for (int r = 0; r < 8; ++r) {
      float p = Pt[nl * 8 + r][k];
      acc[r].x += p * g.x; acc[r].y += p * g.y; acc[r].z += p * g.z; acc[r].w += p * g.w;
    }
  }
#pragma unroll
  for (int r = 0; r < 8; ++r) {
    int n = n0 + nl * 8 + r;
    if (n < N) {
      float4 x = ((const float4*)X)[(size_t)n * 32 + j4];
      float4 o = make_float4(GAMMA_C * acc[r].x + x.x, GAMMA_C * acc[r].y + x.y,
                             GAMMA_C * acc[r].z + x.z, GAMMA_C * acc[r].w + x.w);
      ((float4*)Z)[(size_t)n * 32 + j4] = o;
    }
  }
}

extern "C" void kernel_launch(void* const* d_in, const int* in_sizes, int n_in,
                              void* d_out, int out_size, void* d_ws, size_t ws_size,
                              hipStream_t stream) {
  const float* X  = (const float*)d_in[0];
  const float* F  = (const float*)d_in[1];
  const int* esrc = (const int*)d_in[2];
  const int* edst = (const int*)d_in[3];
  const float* ew = (const float*)d_in[4];
  int N = in_sizes[0] / MDIM;
  int E = in_sizes[2];
  float* Z = (float*)d_out;

  char* ws = (char*)d_ws;
  size_t off = 0;
  auto alloc = [&](size_t bytes) -> void* {
    off = (off + 255) & ~(size_t)255;
    void* p = ws + off;
    off += bytes;
    return p;
  };
  float* P1  = (float*)alloc((size_t)N * MDIM * 4);
  float* P2  = (float*)alloc((size_t)N * MDIM * 4);
  int2*  csr = (int2*)alloc((size_t)E * 8);
  int* offs  = (int*)alloc((size_t)(N + 1) * 4);
  int* deg   = (int*)alloc((size_t)N * 4);
  int* cur   = (int*)alloc((size_t)N * 4);
  float* FF  = (float*)alloc((size_t)MDIM * MDIM * 4);
  float* s   = (float*)alloc(256);

  hipMemsetAsync(deg, 0, (size_t)N * 4, stream);
  hipMemsetAsync(cur, 0, (size_t)N * 4, stream);
  hipMemsetAsync(s, 0, 4, stream);

  int eb = (E + 255) / 256;
  hist_kernel<<<eb, 256, 0, stream>>>(edst, deg, E);
  scan_kernel<<<1, 1024, 0, stream>>>(deg, offs, N);
  scatter_kernel<<<eb, 256, 0, stream>>>(esrc, edst, ew, offs, cur, csr, E);

  ff_kernel<<<64, 256, 0, stream>>>(F, FF);
  normsq_kernel<<<64, 256, 0, stream>>>(FF, s);
  scale_kernel<<<64, 256, 0, stream>>>(FF, s);   // FF becomes gF in place

  // Z = X  (== inner(0))
  hipMemcpyAsync(Z, X, (size_t)N * MDIM * 4, hipMemcpyDeviceToDevice, stream);

  int pb = (N + 7) / 8;
  int gb = (N + 63) / 64;
  for (int it = 0; it < ITERS; ++it) {
    prop_kernel<<<pb, 256, 0, stream>>>((const float4*)Z,  (float4*)P1, offs, csr, N);
    prop_kernel<<<pb, 256, 0, stream>>>((const float4*)P1, (float4*)P2, offs, csr, N);
    gemm_kernel<<<gb, 256, 0, stream>>>(P2, X, Z, FF, N);
  }
}

// Round 2
// 1943.890 us; speedup vs baseline: 2.8556x; 2.8556x over previous
//
#include <hip/hip_runtime.h>
#include <hip/hip_fp16.h>

constexpr int MDIM = 128;          // feature dim
constexpr float GAMMA_C = 0.8f;
constexpr int ITERS = 12;          // slow mode rho~0.25 -> rho^12 ~ 6e-8 of ||X-Z*||

// ---------------- CSR build ----------------
__global__ void hist_kernel(const int* __restrict__ dst, int* __restrict__ deg, int E) {
  int e = blockIdx.x * 256 + threadIdx.x;
  if (e < E) atomicAdd(&deg[dst[e]], 1);
}

__global__ __launch_bounds__(1024) void scan_kernel(const int* __restrict__ deg,
                                                    int* __restrict__ offs, int n) {
  __shared__ int buf[1024];
  __shared__ int carry_s;
  int t = threadIdx.x;
  if (t == 0) carry_s = 0;
  __syncthreads();
  for (int base = 0; base < n; base += 1024) {
    int v = (base + t < n) ? deg[base + t] : 0;
    buf[t] = v;
    __syncthreads();
    for (int off = 1; off < 1024; off <<= 1) {
      int x = (t >= off) ? buf[t - off] : 0;
      __syncthreads();
      buf[t] += x;
      __syncthreads();
    }
    int incl = buf[t];
    if (base + t < n) offs[base + t] = carry_s + incl - v;   // exclusive
    __syncthreads();
    if (t == 1023) carry_s = carry_s + incl;
    __syncthreads();
  }
  if (t == 0) offs[n] = carry_s;
}

__global__ void scatter_kernel(const int* __restrict__ src, const int* __restrict__ dst,
                               const float* __restrict__ w, const int* __restrict__ offs,
                               int* __restrict__ cur, int2* __restrict__ csr, int E) {
  int e = blockIdx.x * 256 + threadIdx.x;
  if (e < E) {
    int d = dst[e];
    int pos = offs[d] + atomicAdd(&cur[d], 1);
    csr[pos] = make_int2(src[e], __float_as_int(w[e]));
  }
}

// ---------------- gF = F^T F / (||F^T F||_F + eps) ----------------
__global__ void ff_kernel(const float* __restrict__ F, float* __restrict__ FF) {
  int idx = blockIdx.x * 256 + threadIdx.x;   // 16384 total
  int i = idx >> 7, j = idx & 127;
  float acc = 0.f;
  for (int k = 0; k < 128; ++k) acc += F[k * 128 + i] * F[k * 128 + j];
  FF[idx] = acc;
}

__global__ void normsq_kernel(const float* __restrict__ FF, float* __restrict__ s) {
  int idx = blockIdx.x * 256 + threadIdx.x;
  float v = FF[idx];
  float v2 = v * v;
  for (int off = 32; off > 0; off >>= 1) v2 += __shfl_down(v2, off, 64);
  __shared__ float partial[4];
  int lane = threadIdx.x & 63, wv = threadIdx.x >> 6;
  if (lane == 0) partial[wv] = v2;
  __syncthreads();
  if (threadIdx.x == 0) atomicAdd(s, partial[0] + partial[1] + partial[2] + partial[3]);
}

__global__ void scale_kernel(float* __restrict__ FF, const float* __restrict__ s) {
  int idx = blockIdx.x * 256 + threadIdx.x;
  FF[idx] *= 1.0f / (sqrtf(*s) + 1e-12f);
}

// ---------------- X -> fp16 ----------------
__global__ void x2h_kernel(const float4* __restrict__ X4, float2* __restrict__ Zh2, int n4) {
  int i = blockIdx.x * 256 + threadIdx.x;
  if (i < n4) {
    float4 v = X4[i];
    union { float2 f; __half2 h[2]; } u;
    u.h[0] = __float22half2_rn(make_float2(v.x, v.y));
    u.h[1] = __float22half2_rn(make_float2(v.z, v.w));
    Zh2[i] = u.f;
  }
}

// ---------------- propagation: P[n] = sum_e w_e * Z[src_e], fp16 rows ----------------
// 16 lanes per node, one float4 (8 halves) per lane; fp32 accumulate; fp16 out.
__device__ __forceinline__ void acc8(float* acc, float w, float4 r) {
  union { float4 f; __half2 h[4]; } u; u.f = r;
#pragma unroll
  for (int k = 0; k < 4; ++k) {
    float2 f = __half22float2(u.h[k]);
    acc[2 * k]     += w * f.x;
    acc[2 * k + 1] += w * f.y;
  }
}

__global__ __launch_bounds__(256) void prop_h_kernel(const float4* __restrict__ Zh4,
                                                     float4* __restrict__ Ph4,
                                                     const int* __restrict__ offs,
                                                     const int2* __restrict__ csr, int N) {
  int t = threadIdx.x & 15;
  int node = blockIdx.x * 16 + (threadIdx.x >> 4);
  if (node >= N) return;
  int beg = offs[node], end = offs[node + 1];
  float acc[8] = {0.f, 0.f, 0.f, 0.f, 0.f, 0.f, 0.f, 0.f};
  int e = beg;
  for (; e + 2 <= end; e += 2) {                 // unroll-2: two gathers in flight
    int2 s0 = csr[e];
    int2 s1 = csr[e + 1];
    float4 r0 = Zh4[(size_t)s0.x * 16 + t];
    float4 r1 = Zh4[(size_t)s1.x * 16 + t];
    acc8(acc, __int_as_float(s0.y), r0);
    acc8(acc, __int_as_float(s1.y), r1);
  }
  if (e < end) {
    int2 s0 = csr[e];
    float4 r0 = Zh4[(size_t)s0.x * 16 + t];
    acc8(acc, __int_as_float(s0.y), r0);
  }
  union { float4 f; __half2 h[4]; } o;
#pragma unroll
  for (int k = 0; k < 4; ++k)
    o.h[k] = __float22half2_rn(make_float2(acc[2 * k], acc[2 * k + 1]));
  Ph4[(size_t)node * 16 + t] = o.f;
}

// ---------------- Z = gamma * P @ gF + X  (gF symmetric); also writes Zh fp16 ----------------
__global__ __launch_bounds__(256) void gemm_kernel(const float4* __restrict__ P2h4,
                                                   const float* __restrict__ X,
                                                   float* __restrict__ Z,
                                                   float2* __restrict__ Zh2,
                                                   const float* __restrict__ gF, int N) {
  __shared__ float Pt[64][128];
  int n0 = blockIdx.x * 64;
  int rows = min(64, N - n0);
  int nchunks = rows * 16;                       // fp16 float4-chunks
  const float4* base = P2h4 + (size_t)n0 * 16;
  for (int i = threadIdx.x; i < nchunks; i += 256) {
    union { float4 f; __half2 h[4]; } u; u.f = base[i];
    int r = i >> 4, c = i & 15;
    float* dst = &Pt[r][c * 8];
    float2 f0 = __half22float2(u.h[0]);
    float2 f1 = __half22float2(u.h[1]);
    float2 f2 = __half22float2(u.h[2]);
    float2 f3 = __half22float2(u.h[3]);
    dst[0] = f0.x; dst[1] = f0.y; dst[2] = f1.x; dst[3] = f1.y;
    dst[4] = f2.x; dst[5] = f2.y; dst[6] = f3.x; dst[7] = f3.y;
  }
  __syncthreads();
  int j4 = threadIdx.x & 31;
  int nl = threadIdx.x >> 5;                     // 0..7, 8 nodes each
  float4 acc[8];
#pragma unroll
  for (int r = 0; r < 8; ++r) acc[r] = make_float4(0.f, 0.f, 0.f, 0.f);
  const float4* g4 = (const float4*)gF;
#pragma unroll 4
  for (int k = 0; k < 128; ++k) {
    float4 g = g4[k * 32 + j4];
#pragma unroll
    for (int r = 0; r < 8; ++r) {
      float p = Pt[nl * 8 + r][k];
      acc[r].x += p * g.x; acc[r].y += p * g.y; acc[r].z += p * g.z; acc[r].w += p * g.w;
    }
  }
#pragma unroll
  for (int r = 0; r < 8; ++r) {
    int n = n0 + nl * 8 + r;
    if (n < N) {
      size_t idx = (size_t)n * 32 + j4;
      float4 x = ((const float4*)X)[idx];
      float4 o = make_float4(GAMMA_C * acc[r].x + x.x, GAMMA_C * acc[r].y + x.y,
                             GAMMA_C * acc[r].z + x.z, GAMMA_C * acc[r].w + x.w);
      ((float4*)Z)[idx] = o;
      union { float2 f; __half2 h[2]; } zo;
      zo.h[0] = __float22half2_rn(make_float2(o.x, o.y));
      zo.h[1] = __float22half2_rn(make_float2(o.z, o.w));
      Zh2[idx] = zo.f;
    }
  }
}

extern "C" void kernel_launch(void* const* d_in, const int* in_sizes, int n_in,
                              void* d_out, int out_size, void* d_ws, size_t ws_size,
                              hipStream_t stream) {
  const float* X  = (const float*)d_in[0];
  const float* F  = (const float*)d_in[1];
  const int* esrc = (const int*)d_in[2];
  const int* edst = (const int*)d_in[3];
  const float* ew = (const float*)d_in[4];
  int N = in_sizes[0] / MDIM;
  int E = in_sizes[2];
  float* Z = (float*)d_out;

  char* ws = (char*)d_ws;
  size_t off = 0;
  auto alloc = [&](size_t bytes) -> void* {
    off = (off + 255) & ~(size_t)255;
    void* p = ws + off;
    off += bytes;
    return p;
  };
  __half* Zh  = (__half*)alloc((size_t)N * MDIM * 2);
  __half* P1h = (__half*)alloc((size_t)N * MDIM * 2);
  __half* P2h = (__half*)alloc((size_t)N * MDIM * 2);
  int2*  csr = (int2*)alloc((size_t)E * 8);
  int* offs  = (int*)alloc((size_t)(N + 1) * 4);
  int* deg   = (int*)alloc((size_t)N * 4);
  int* cur   = (int*)alloc((size_t)N * 4);
  float* FF  = (float*)alloc((size_t)MDIM * MDIM * 4);
  float* s   = (float*)alloc(256);

  hipMemsetAsync(deg, 0, (size_t)N * 4, stream);
  hipMemsetAsync(cur, 0, (size_t)N * 4, stream);
  hipMemsetAsync(s, 0, 4, stream);

  int eb = (E + 255) / 256;
  hist_kernel<<<eb, 256, 0, stream>>>(edst, deg, E);
  scan_kernel<<<1, 1024, 0, stream>>>(deg, offs, N);
  scatter_kernel<<<eb, 256, 0, stream>>>(esrc, edst, ew, offs, cur, csr, E);

  ff_kernel<<<64, 256, 0, stream>>>(F, FF);
  normsq_kernel<<<64, 256, 0, stream>>>(FF, s);
  scale_kernel<<<64, 256, 0, stream>>>(FF, s);   // FF becomes gF in place

  int n4 = N * (MDIM / 4);                        // float4 chunks of X
  x2h_kernel<<<(n4 + 255) / 256, 256, 0, stream>>>((const float4*)X, (float2*)Zh, n4);

  int pb = (N + 15) / 16;
  int gb = (N + 63) / 64;
  for (int it = 0; it < ITERS; ++it) {
    prop_h_kernel<<<pb, 256, 0, stream>>>((const float4*)Zh,  (float4*)P1h, offs, csr, N);
    prop_h_kernel<<<pb, 256, 0, stream>>>((const float4*)P1h, (float4*)P2h, offs, csr, N);
    gemm_kernel<<<gb, 256, 0, stream>>>((const float4*)P2h, X, Z, (float2*)Zh, FF, N);
  }
}